// Round 4
// baseline (490.844 us; speedup 1.0000x reference)
//
#include <hip/hip_runtime.h>
#include <math.h>

#define N_OCT  32
#define N_SMP  32768
#define N_PAIR 64          // B*E = 4*16
#define BPP    64          // blocks per pair: 512 samples/block, 2/thread

// ---------------------------------------------------------------------------
// Single fused kernel.
//  Prologue: lanes 0-31 recompute the pair's (w,a) — the freq cumsum keeps
//    the reference's EXACT sequential fp32 rounding (lane o captures the
//    running sum at step o). w is stored pre-divided by 2pi (revolutions).
//  Body: 2 samples/thread, per octave: mul + fract + v_sin + fma.
//  Epilogue: block max -> bmax; last block per pair (device-scope counter)
//    reduces the 64 maxes and normalizes the pair's 32768 samples in place.
// ---------------------------------------------------------------------------
__global__ __launch_bounds__(256) void f0res_fused(
    const float* __restrict__ f0_in,
    const float* __restrict__ dec_in,
    const float* __restrict__ fs_in,
    float* __restrict__ out,
    float* __restrict__ bmax,        // [N_PAIR][BPP]
    unsigned* __restrict__ cnt)      // [N_PAIR], zeroed by memset node
{
    __shared__ __align__(16) float sw[N_OCT];
    __shared__ __align__(16) float sa[N_OCT];
    __shared__ float wm[4];
    __shared__ int   is_last;

    const int pair = blockIdx.x >> 6;
    const int blk  = blockIdx.x & (BPP - 1);
    const int tid  = threadIdx.x;

    // ---- in-block setup (replaces the setup kernel) ----
    if (tid < N_OCT) {
        const float minf   = (float)(20.0 / 11025.0);
        const float frange = (float)(3000.0 / 11025.0 - 20.0 / 11025.0);
        const float pif    = 3.14159265358979323846f;
        const float INV2PI = 0.15915494309189535f;

        float f0 = fabsf(f0_in[pair]);
        float fs = fs_in[pair];
        float x  = dec_in[pair];

        float s1 = 1.0f / (1.0f + expf(-x));      // double sigmoid (ref quirk)
        float s2 = 1.0f / (1.0f + expf(-s1));
        float d  = 0.01f + s2 * (float)(0.99 * 0.99);
        float ld = logf(d + 1e-12f);
        float f0p = (minf + f0 * frange) * pif;

        // sequential fp32 cumsums — bit-match the reference rounding order;
        // lane o captures the partial sums at step o (parallel, exact).
        float fac = 0.0f, acl = 0.0f, myfac = 0.0f, myacl = 0.0f;
#pragma unroll
        for (int o = 0; o < N_OCT; ++o) {
            fac += fs;
            acl += ld;
            if (o == tid) { myfac = fac; myacl = acl; }
        }
        float f0s = f0p * myfac;
        sw[tid] = (f0s < 1.0f) ? f0s * INV2PI : 0.0f;   // Nyquist mask; sin(0)=0
        sa[tid] = expf(myacl);                          // d^(o+1)
    }
    __syncthreads();

    // preload (w,a) into registers: 16 x ds_read_b128, same-addr broadcast
    float4 wv[8], av[8];
    const float4* w4 = (const float4*)sw;
    const float4* a4 = (const float4*)sa;
#pragma unroll
    for (int i = 0; i < 8; ++i) { wv[i] = w4[i]; av[i] = a4[i]; }

    const int   s0 = (blk << 9) + tid;          // this thread: s0 and s0+256
    const float t0 = (float)(s0 + 1);           // t = s+1, exact in fp32
    const float t1 = (float)(s0 + 257);

    float acc0 = 0.0f, acc1 = 0.0f;
#pragma unroll
    for (int i = 0; i < 8; ++i) {
        const float wr[4] = { wv[i].x, wv[i].y, wv[i].z, wv[i].w };
        const float ar[4] = { av[i].x, av[i].y, av[i].z, av[i].w };
#pragma unroll
        for (int j = 0; j < 4; ++j) {
            float r0 = wr[j] * t0;
            float r1 = wr[j] * t1;
            acc0 = fmaf(ar[j], __builtin_amdgcn_sinf(__builtin_amdgcn_fractf(r0)), acc0);
            acc1 = fmaf(ar[j], __builtin_amdgcn_sinf(__builtin_amdgcn_fractf(r1)), acc1);
        }
    }

    float* op = out + pair * N_SMP + s0;
    op[0]   = acc0;
    op[256] = acc1;

    // ---- block max ----
    float av_ = fmaxf(fabsf(acc0), fabsf(acc1));
#pragma unroll
    for (int m = 32; m >= 1; m >>= 1)
        av_ = fmaxf(av_, __shfl_xor(av_, m, 64));
    if ((tid & 63) == 0) wm[tid >> 6] = av_;

    // release: make every thread's out[] stores visible device-wide
    __threadfence();
    __syncthreads();

    if (tid == 0) {
        bmax[pair * BPP + blk] =
            fmaxf(fmaxf(wm[0], wm[1]), fmaxf(wm[2], wm[3]));
        __threadfence();                         // bmax before the count bump
        unsigned old = atomicAdd(&cnt[pair], 1u);
        is_last = (old == BPP - 1) ? 1 : 0;
    }
    __syncthreads();

    // ---- last block of the pair normalizes in place ----
    if (is_last) {
        __threadfence();                         // acquire other blocks' writes

        float v = (tid < BPP) ? bmax[pair * BPP + tid] : 0.0f;
#pragma unroll
        for (int m = 32; m >= 1; m >>= 1)
            v = fmaxf(v, __shfl_xor(v, m, 64));
        if ((tid & 63) == 0) wm[tid >> 6] = v;   // waves 1-3 contribute 0
        __syncthreads();
        const float mx  = fmaxf(fmaxf(wm[0], wm[1]), fmaxf(wm[2], wm[3])) + 1e-8f;
        const float inv = 1.0f / mx;

        float4* o4 = (float4*)(out + pair * N_SMP);
#pragma unroll 4
        for (int i = tid; i < N_SMP / 4; i += 256) {
            float4 val = o4[i];
            val.x *= inv; val.y *= inv; val.z *= inv; val.w *= inv;
            o4[i] = val;
        }
    }
}

extern "C" void kernel_launch(void* const* d_in, const int* in_sizes, int n_in,
                              void* d_out, int out_size, void* d_ws, size_t ws_size,
                              hipStream_t stream) {
    const float* f0  = (const float*)d_in[0];
    const float* dec = (const float*)d_in[1];
    const float* fs  = (const float*)d_in[2];
    float* out = (float*)d_out;

    unsigned* cnt  = (unsigned*)d_ws;                    // 64 uints
    float*    bmax = (float*)((char*)d_ws + 256);        // 64*64 floats

    hipMemsetAsync(cnt, 0, N_PAIR * sizeof(unsigned), stream);  // capture-legal
    f0res_fused<<<N_PAIR * BPP, 256, 0, stream>>>(f0, dec, fs, out, bmax, cnt);
}

// Round 5
// 74.176 us; speedup vs baseline: 6.6172x; 6.6172x over previous
//
#include <hip/hip_runtime.h>
#include <math.h>

#define N_OCT  32
#define N_SMP  32768
#define N_PAIR 64          // B*E = 4*16
#define BPP    32          // blocks per pair: 1024 samples/block, 4/thread

// ---------------------------------------------------------------------------
// Kernel 1: oscillator bank. Per-block prologue (wave 0) recomputes the
// pair's (w,a) with the reference's EXACT sequential fp32 cumsum rounding
// (lane o captures the running sum at step o). w stored pre-divided by 2pi
// so the body is mul + v_fract + v_sin + v_fma per octave-sample.
// 4 samples/thread. Per-block max stored plainly (kernel boundary = sync;
// NO fences/atomics — R4 showed per-block device-scope fences cost ~420us).
// ---------------------------------------------------------------------------
__global__ __launch_bounds__(256) void f0res_osc(
    const float* __restrict__ f0_in,
    const float* __restrict__ dec_in,
    const float* __restrict__ fs_in,
    float* __restrict__ out,
    float* __restrict__ bmax)        // [N_PAIR][BPP]
{
    __shared__ __align__(16) float sw[N_OCT];
    __shared__ __align__(16) float sa[N_OCT];

    const int pair = blockIdx.x >> 5;
    const int blk  = blockIdx.x & (BPP - 1);
    const int tid  = threadIdx.x;

    // ---- in-block setup (lanes 0-31 of wave 0) ----
    if (tid < N_OCT) {
        const float minf   = (float)(20.0 / 11025.0);
        const float frange = (float)(3000.0 / 11025.0 - 20.0 / 11025.0);
        const float pif    = 3.14159265358979323846f;
        const float INV2PI = 0.15915494309189535f;

        float f0 = fabsf(f0_in[pair]);
        float fs = fs_in[pair];
        float x  = dec_in[pair];

        float s1 = 1.0f / (1.0f + expf(-x));      // double sigmoid (ref quirk)
        float s2 = 1.0f / (1.0f + expf(-s1));
        float d  = 0.01f + s2 * (float)(0.99 * 0.99);
        float ld = logf(d + 1e-12f);
        float f0p = (minf + f0 * frange) * pif;

        // sequential fp32 cumsums — bit-match the reference rounding order
        float fac = 0.0f, acl = 0.0f, myfac = 0.0f, myacl = 0.0f;
#pragma unroll
        for (int o = 0; o < N_OCT; ++o) {
            fac += fs;
            acl += ld;
            if (o == tid) { myfac = fac; myacl = acl; }
        }
        float f0s = f0p * myfac;
        sw[tid] = (f0s < 1.0f) ? f0s * INV2PI : 0.0f;   // Nyquist mask; sin(0)=0
        sa[tid] = expf(myacl);                          // d^(o+1)
    }
    __syncthreads();

    // preload (w,a): 16 x ds_read_b128 same-address broadcast (conflict-free)
    float4 wv[8], av[8];
    const float4* w4 = (const float4*)sw;
    const float4* a4 = (const float4*)sa;
#pragma unroll
    for (int i = 0; i < 8; ++i) { wv[i] = w4[i]; av[i] = a4[i]; }

    const int   s0 = (blk << 10) + tid;         // samples s0 + {0,256,512,768}
    const float t0 = (float)(s0 + 1);           // t = s+1, exact in fp32
    const float t1 = (float)(s0 + 257);
    const float t2 = (float)(s0 + 513);
    const float t3 = (float)(s0 + 769);

    float acc0 = 0.0f, acc1 = 0.0f, acc2 = 0.0f, acc3 = 0.0f;
#pragma unroll
    for (int i = 0; i < 8; ++i) {
        const float wr[4] = { wv[i].x, wv[i].y, wv[i].z, wv[i].w };
        const float ar[4] = { av[i].x, av[i].y, av[i].z, av[i].w };
#pragma unroll
        for (int j = 0; j < 4; ++j) {
            float w = wr[j], a = ar[j];
            acc0 = fmaf(a, __builtin_amdgcn_sinf(__builtin_amdgcn_fractf(w * t0)), acc0);
            acc1 = fmaf(a, __builtin_amdgcn_sinf(__builtin_amdgcn_fractf(w * t1)), acc1);
            acc2 = fmaf(a, __builtin_amdgcn_sinf(__builtin_amdgcn_fractf(w * t2)), acc2);
            acc3 = fmaf(a, __builtin_amdgcn_sinf(__builtin_amdgcn_fractf(w * t3)), acc3);
        }
    }

    float* op = out + pair * N_SMP + s0;
    op[0]   = acc0;
    op[256] = acc1;
    op[512] = acc2;
    op[768] = acc3;

    // ---- block max -> one plain store (no atomics, no init needed) ----
    float av_ = fmaxf(fmaxf(fabsf(acc0), fabsf(acc1)),
                      fmaxf(fabsf(acc2), fabsf(acc3)));
#pragma unroll
    for (int m = 32; m >= 1; m >>= 1)
        av_ = fmaxf(av_, __shfl_xor(av_, m, 64));
    __shared__ float wm[4];
    if ((tid & 63) == 0) wm[tid >> 6] = av_;
    __syncthreads();
    if (tid == 0)
        bmax[pair * BPP + blk] = fmaxf(fmaxf(wm[0], wm[1]), fmaxf(wm[2], wm[3]));
}

// ---------------------------------------------------------------------------
// Kernel 2: reduce the 32 per-block maxes, then normalize (float4, L2-hot).
// ---------------------------------------------------------------------------
__global__ __launch_bounds__(256) void f0res_norm(
    float* __restrict__ out, const float* __restrict__ bmax)
{
    const int pair = blockIdx.x >> 5;                   // 32 blocks per pair
    const int tid  = threadIdx.x;

    float v = (tid < BPP) ? bmax[pair * BPP + tid] : 0.0f;
#pragma unroll
    for (int m = 16; m >= 1; m >>= 1)
        v = fmaxf(v, __shfl_xor(v, m, 64));
    v = __shfl(v, 0, 64);                               // wave 0 has the max
    __shared__ float smx;
    if (tid == 0) smx = v;
    __syncthreads();
    const float inv = 1.0f / (smx + 1e-8f);

    const int idx = ((blockIdx.x & 31) << 8) + tid;     // 256 float4 per block
    float4* o4 = (float4*)(out + pair * N_SMP);
    float4 val = o4[idx];
    val.x *= inv; val.y *= inv; val.z *= inv; val.w *= inv;
    o4[idx] = val;
}

extern "C" void kernel_launch(void* const* d_in, const int* in_sizes, int n_in,
                              void* d_out, int out_size, void* d_ws, size_t ws_size,
                              hipStream_t stream) {
    const float* f0  = (const float*)d_in[0];
    const float* dec = (const float*)d_in[1];
    const float* fs  = (const float*)d_in[2];
    float* out = (float*)d_out;

    float* bmax = (float*)d_ws;                 // 64*32 floats

    f0res_osc <<<N_PAIR * BPP, 256, 0, stream>>>(f0, dec, fs, out, bmax);
    f0res_norm<<<N_PAIR * 32,  256, 0, stream>>>(out, bmax);
}